// Round 1
// 381.962 us; speedup vs baseline: 1.1955x; 1.1955x over previous
//
#include <hip/hip_runtime.h>

// MDTA (Restormer): b=8, c=192, h=w=128, nh=8, hd=24.
// Round 6: gemm_mfma was serialization-bound (MfmaUtil 7.5%, HBM 16.5%,
// 80 cyc/store-instr from 144 scalar 2B scattered stores per thread).
// Fixes: (1) C-tile transpose through LDS -> dwordx4 coalesced stores,
// (2) A matrices pre-shuffled to MFMA fragment order -> 1KB contiguous
// wave loads, (3) two-phase B staging cuts LDS 48->32KB -> 4 blocks/CU,
// grid 1024 = exactly one occupancy round.

#define HW 16384
#define WIMG 128
#define C 192
#define C3 576
#define NH 8
#define HD 24

typedef unsigned short ushort8_t __attribute__((ext_vector_type(8)));
typedef short short8_t __attribute__((ext_vector_type(8)));
typedef float float4_t __attribute__((ext_vector_type(4)));

__device__ __forceinline__ float bfu2f(unsigned short u) {
    union { unsigned int i; float f; } v; v.i = ((unsigned int)u) << 16; return v.f;
}
__device__ __forceinline__ unsigned short f2bfu(float f) {
    union { float f; unsigned int i; } v; v.f = f;
    unsigned int x = v.i;
    return (unsigned short)((x + 0x7FFFu + ((x >> 16) & 1u)) >> 16);
}
__device__ __forceinline__ float inload(const void* p, int idx, int isbf) {
    return isbf ? bfu2f(((const unsigned short*)p)[idx]) : ((const float*)p)[idx];
}

// MFMA A-fragment permutation for a [rows x 192] bf16 matrix:
// (o,dg) -> (((o>>4)*6 + (dg>>5))*4 + ((dg>>3)&3))*128 + (o&15)*8 + (dg&7)
__device__ __forceinline__ int afrag_idx(int o, int dg) {
    return ((((o >> 4) * 6 + (dg >> 5)) * 4 + ((dg >> 3) & 3)) << 7)
           + ((o & 15) << 3) + (dg & 7);
}

// dtype probe: bf16-packed x -> low ushort of u32 is an N(0,1) bf16 (exp in
// [100,140]); fp32 x -> low ushort is uniform mantissa bits (~16% hit).
__global__ void probe_dtype(const unsigned int* __restrict__ x, int* __restrict__ flag) {
    const int t = threadIdx.x;
    int cnt = 0;
    for (int i = t; i < 512; i += 256) {
        const unsigned int u = x[i] & 0xFFFFu;
        const unsigned int e = (u >> 7) & 0xFFu;
        if (u == 0u || (e >= 100u && e <= 140u)) cnt++;
    }
#pragma unroll
    for (int off = 32; off; off >>= 1) cnt += __shfl_down(cnt, off, 64);
    __shared__ int s[4];
    if ((t & 63) == 0) s[t >> 6] = cnt;
    __syncthreads();
    if (t == 0) flag[0] = (s[0] + s[1] + s[2] + s[3] > 300) ? 1 : 0;
}

// Convert weights once (wqkv into MFMA fragment order); zero Sraw + normsum.
// ws is re-poisoned before every timed call, so this runs every call.
__global__ void prep(const void* __restrict__ wqkv, const void* __restrict__ wdw,
                     const void* __restrict__ wout, const void* __restrict__ temp,
                     const int* __restrict__ flagp, unsigned short* __restrict__ wqb,
                     float* __restrict__ wdwf, float* __restrict__ woutf,
                     float* __restrict__ tempf, float* __restrict__ Sraw,
                     float* __restrict__ normsum) {
    const int isbf = flagp[0];
    const int id = blockIdx.x * 256 + threadIdx.x;
    const int stride = gridDim.x * 256;
    for (int i = id; i < C3 * C; i += stride) {
        const int o = i / C, dg = i - o * C;
        const unsigned short v =
            isbf ? ((const unsigned short*)wqkv)[i] : f2bfu(((const float*)wqkv)[i]);
        wqb[afrag_idx(o, dg)] = v;
    }
    for (int i = id; i < C3 * 9; i += stride) wdwf[i] = inload(wdw, i, isbf);
    for (int i = id; i < C * C; i += stride) woutf[i] = inload(wout, i, isbf);
    for (int i = id; i < NH; i += stride) tempf[i] = inload(temp, i, isbf);
    for (int i = id; i < 8 * NH * HD * HD; i += stride) Sraw[i] = 0.f;
    for (int i = id; i < 8 * 2 * C; i += stride) normsum[i] = 0.f;
}

// GEMM via MFMA 16x16x32 bf16: out[m_tiles*64 x HW] = A[. x 192] * B[192 x HW],
// batched over blockIdx.y.  B tile [192x128] staged in two 96-channel phases
// into a 32KB XOR-swizzled LDS buffer (conflict-free ds_read_b128); B-frags
// preloaded to registers; A is pre-shuffled to fragment order (1KB contiguous
// wave loads).  bf16 epilogue: C-tile transposed through LDS -> dwordx4
// coalesced stores (fp32 epilogue falls back to scalar dword stores).
__global__ __launch_bounds__(512) void gemm_mfma(
    const void* __restrict__ Bsrc, const unsigned short* __restrict__ Abf,
    void* __restrict__ outp, const int* __restrict__ flagp,
    size_t b_batch_stride, size_t b_const_off, size_t o_batch_stride,
    int a_batch_stride, int m_tiles, int b_mode, int out_mode) {
    __shared__ unsigned short sbuf[16384];  // 32 KB: B half-tile stage / C transpose
    const int isbf = flagp[0];
    const int b_isbf = b_mode | isbf;
    const int tid = threadIdx.x;
    const int batch = blockIdx.y;
    const int n0 = blockIdx.x * 128;
    const size_t b_off = b_batch_stride * batch + b_const_off;
    const size_t o_off = o_batch_stride * batch;
    const unsigned short* Ab = Abf + (size_t)a_batch_stride * batch;

    const int w = tid >> 6;
    const int lane = tid & 63;
    const int l15 = lane & 15;
    const int quad = lane >> 4;
    const int mhalf = w & 1;
    const int nquad = w >> 1;

    short8_t bfr[6][2];
#pragma unroll
    for (int h = 0; h < 2; h++) {
        if (h) __syncthreads();  // all waves finished reading phase-0 frags
        if (tid < 192) {
            const int cg = tid >> 4;   // [0,12) local c-chunk of 8
            const int pg = tid & 15;   // [0,16) pixel-group of 8
            const int chbase = h * 96 + cg * 8;
            ushort8_t rows[8];
            if (b_isbf) {
                const unsigned short* bp = (const unsigned short*)Bsrc + b_off + n0 + pg * 8;
#pragma unroll
                for (int r = 0; r < 8; r++)
                    rows[r] = *reinterpret_cast<const ushort8_t*>(bp + (size_t)(chbase + r) * HW);
            } else {
                const float* bp = (const float*)Bsrc + b_off + n0 + pg * 8;
#pragma unroll
                for (int r = 0; r < 8; r++) {
                    const float4_t f0 = *reinterpret_cast<const float4_t*>(bp + (size_t)(chbase + r) * HW);
                    const float4_t f1 = *reinterpret_cast<const float4_t*>(bp + (size_t)(chbase + r) * HW + 4);
#pragma unroll
                    for (int i = 0; i < 4; i++) { rows[r][i] = f2bfu(f0[i]); rows[r][i + 4] = f2bfu(f1[i]); }
                }
            }
#pragma unroll
            for (int s = 0; s < 8; s++) {
                ushort8_t outv;
#pragma unroll
                for (int r = 0; r < 8; r++) outv[r] = rows[r][s];
                const int p = pg * 8 + s;
                const int cidx = p * 16 + (cg ^ s);  // s == p&7
                *reinterpret_cast<ushort8_t*>(&sbuf[cidx * 8]) = outv;
            }
        }
        __syncthreads();
#pragma unroll
        for (int ksl = 0; ksl < 3; ksl++) {
            const int ks = h * 3 + ksl;
            const int cgl = ks * 4 + quad - h * 12;  // [0,12) within this phase
#pragma unroll
            for (int nt = 0; nt < 2; nt++) {
                const int p = nquad * 32 + nt * 16 + l15;
                const int cidx = p * 16 + (cgl ^ (p & 7));
                bfr[ks][nt] = *reinterpret_cast<const short8_t*>(&sbuf[cidx * 8]);
            }
        }
    }

    const int o_isbf = out_mode ? isbf : 1;
    const int rr = tid >> 3;   // transpose-store: row of 64-row C tile
    const int kk = tid & 7;    // transpose-store: 16-px segment
    for (int mt0 = 0; mt0 < m_tiles; mt0++) {
        const int m0 = mt0 * 64;
        short8_t afr[2][6];
#pragma unroll
        for (int mt = 0; mt < 2; mt++) {
            const int tile = mt0 * 4 + mhalf * 2 + mt;
#pragma unroll
            for (int ks = 0; ks < 6; ks++)
                afr[mt][ks] = *reinterpret_cast<const short8_t*>(
                    Ab + (size_t)((((tile * 6 + ks) << 2) + quad) << 7) + (l15 << 3));
        }
        float4_t acc[2][2];
#pragma unroll
        for (int mt = 0; mt < 2; mt++)
#pragma unroll
            for (int nt = 0; nt < 2; nt++) {
                float4_t z = {0.f, 0.f, 0.f, 0.f};
                acc[mt][nt] = z;
            }
#pragma unroll
        for (int ks = 0; ks < 6; ks++)
#pragma unroll
            for (int mt = 0; mt < 2; mt++)
#pragma unroll
                for (int nt = 0; nt < 2; nt++)
                    acc[mt][nt] = __builtin_amdgcn_mfma_f32_16x16x32_bf16(
                        afr[mt][ks], bfr[ks][nt], acc[mt][nt], 0, 0, 0);
        if (o_isbf) {
            // 64x128 bf16 C tile through LDS (row stride 136 ushorts = 272B:
            // quad pairs 2-way on writes = free), then coalesced 16B stores.
            __syncthreads();
#pragma unroll
            for (int mt = 0; mt < 2; mt++) {
                const int row64 = (mhalf * 2 + mt) * 16 + quad * 4;
#pragma unroll
                for (int nt = 0; nt < 2; nt++) {
                    const int col = nquad * 32 + nt * 16 + l15;
#pragma unroll
                    for (int r = 0; r < 4; r++)
                        sbuf[(row64 + r) * 136 + col] = f2bfu(acc[mt][nt][r]);
                }
            }
            __syncthreads();
            const ushort8_t v0 = *reinterpret_cast<const ushort8_t*>(&sbuf[rr * 136 + kk * 16]);
            const ushort8_t v1 = *reinterpret_cast<const ushort8_t*>(&sbuf[rr * 136 + kk * 16 + 8]);
            unsigned short* op = (unsigned short*)outp + o_off + (size_t)(m0 + rr) * HW + n0 + kk * 16;
            *reinterpret_cast<ushort8_t*>(op) = v0;
            *reinterpret_cast<ushort8_t*>(op + 8) = v1;
        } else {
#pragma unroll
            for (int mt = 0; mt < 2; mt++) {
                const int row = m0 + (mhalf * 2 + mt) * 16 + quad * 4;
#pragma unroll
                for (int nt = 0; nt < 2; nt++) {
                    const int col = n0 + nquad * 32 + nt * 16 + l15;
#pragma unroll
                    for (int r = 0; r < 4; r++)
                        ((float*)outp)[o_off + (size_t)(row + r) * HW + col] = acc[mt][nt][r];
                }
            }
        }
    }
}

// depthwise 3x3 SAME, bf16 in/out, fp32 math, 8 px/thread; q/k channel
// norm-sums accumulated from fp32 pre-store values (one atomic per block).
// grid (8, 576, 8): x = 2048-px slab, y = channel, z = batch.  block 256.
__global__ void dwconv(const unsigned short* __restrict__ qkv0,
                       const float* __restrict__ wdwf,
                       unsigned short* __restrict__ qkv1,
                       float* __restrict__ normsum) {
    const int ch = blockIdx.y;
    const size_t base = (size_t)blockIdx.z * C3 * HW + (size_t)ch * HW;
    const unsigned short* ip = qkv0 + base;
    const float* wp = wdwf + ch * 9;
    const int p = blockIdx.x * 2048 + threadIdx.x * 8;
    const int y = p >> 7, x0 = p & 127;
    float acc[8];
#pragma unroll
    for (int j = 0; j < 8; j++) acc[j] = 0.f;
#pragma unroll
    for (int dy = 0; dy < 3; dy++) {
        const int yy = y + dy - 1;
        if (yy < 0 || yy > 127) continue;
        const int rb = yy * WIMG + x0;
        const ushort8_t mid = *reinterpret_cast<const ushort8_t*>(ip + rb);
        float f[10];
        f[0] = (x0 > 0) ? bfu2f(ip[rb - 1]) : 0.f;
        f[9] = (x0 < 120) ? bfu2f(ip[rb + 8]) : 0.f;
#pragma unroll
        for (int i = 0; i < 8; i++) f[i + 1] = bfu2f(mid[i]);
        const float w0 = wp[dy * 3], w1 = wp[dy * 3 + 1], w2 = wp[dy * 3 + 2];
#pragma unroll
        for (int j = 0; j < 8; j++) acc[j] += w0 * f[j] + w1 * f[j + 1] + w2 * f[j + 2];
    }
    ushort8_t outv;
#pragma unroll
    for (int j = 0; j < 8; j++) outv[j] = f2bfu(acc[j]);
    *reinterpret_cast<ushort8_t*>(qkv1 + base + p) = outv;

    if (ch < 2 * C) {  // q or k channel: accumulate sum of squares
        float ss = 0.f;
#pragma unroll
        for (int j = 0; j < 8; j++) ss += acc[j] * acc[j];
#pragma unroll
        for (int off = 32; off; off >>= 1) ss += __shfl_down(ss, off, 64);
        __shared__ float red[4];
        if ((threadIdx.x & 63) == 0) red[threadIdx.x >> 6] = ss;
        __syncthreads();
        if (threadIdx.x == 0)
            atomicAdd(&normsum[blockIdx.z * 2 * C + ch],
                      red[0] + red[1] + red[2] + red[3]);
    }
}

// Gram S[h] = Q(24xHW) . K^T via MFMA on padded 32x32 tiles.
// grid (8, NH, 8): x = split-group (4 waves -> 32 k-splits of 512), y = h,
// z = b.  block 256 = 4 waves; one wave per k-split; atomicAdd into Sraw.
__global__ __launch_bounds__(256) void attn_gram(
    const unsigned short* __restrict__ qkv1, float* __restrict__ Sraw) {
    const int b = blockIdx.z, h = blockIdx.y;
    const int wave = threadIdx.x >> 6;
    const int lane = threadIdx.x & 63;
    const int l15 = lane & 15, quad = lane >> 4;
    const int k0 = (blockIdx.x * 4 + wave) * 512;
    const unsigned short* qrow = qkv1 + (size_t)b * C3 * HW + (size_t)(h * HD) * HW;
    const unsigned short* krow = qkv1 + (size_t)b * C3 * HW + (size_t)(C + h * HD) * HW;

    float4_t acc[2][2];
#pragma unroll
    for (int mt = 0; mt < 2; mt++)
#pragma unroll
        for (int nt = 0; nt < 2; nt++) {
            float4_t z = {0.f, 0.f, 0.f, 0.f};
            acc[mt][nt] = z;
        }

#pragma unroll 4
    for (int ks = 0; ks < 16; ks++) {
        const int kk = k0 + ks * 32 + quad * 8;
        short8_t qa[2], kb[2];
        qa[0] = *reinterpret_cast<const short8_t*>(qrow + (size_t)l15 * HW + kk);
        qa[1] = *reinterpret_cast<const short8_t*>(qrow + (size_t)(16 + l15) * HW + kk);
        kb[0] = *reinterpret_cast<const short8_t*>(krow + (size_t)l15 * HW + kk);
        kb[1] = *reinterpret_cast<const short8_t*>(krow + (size_t)(16 + l15) * HW + kk);
#pragma unroll
        for (int mt = 0; mt < 2; mt++)
#pragma unroll
            for (int nt = 0; nt < 2; nt++)
                acc[mt][nt] = __builtin_amdgcn_mfma_f32_16x16x32_bf16(
                    qa[mt], kb[nt], acc[mt][nt], 0, 0, 0);
    }

    float* Sb = Sraw + (size_t)b * NH * HD * HD + (size_t)h * HD * HD;
#pragma unroll
    for (int nt = 0; nt < 2; nt++) {
        const int j = nt * 16 + l15;
        if (j >= HD) continue;
#pragma unroll
        for (int mt = 0; mt < 2; mt++) {
            const int i0 = mt * 16 + quad * 4;
#pragma unroll
            for (int r = 0; r < 4; r++) {
                const int i = i0 + r;
                if (i < HD) atomicAdd(&Sb[i * HD + j], acc[mt][nt][r]);
            }
        }
    }
}

// Fused invnorm + softmax + M = Wout * blockdiag(A), bf16.  grid (144, 8).
// M is emitted in MFMA fragment order for gemm2's A-frag loads.
__global__ void buildM(const float* __restrict__ Sraw, const float* __restrict__ normsum,
                       const float* __restrict__ tempf, const float* __restrict__ woutf,
                       unsigned short* __restrict__ Mb) {
    __shared__ float As[NH * HD * HD];
    __shared__ float inv[2 * C];
    const int b = blockIdx.y;
    const int tid = threadIdx.x;
    for (int r = tid; r < 2 * C; r += 256)
        inv[r] = 1.f / fmaxf(sqrtf(normsum[b * 2 * C + r]), 1e-12f);
    __syncthreads();
    for (int e = tid; e < NH * HD * HD; e += 256) {
        const int h = e / (HD * HD);
        const int rm = e - h * HD * HD;
        const int i = rm / HD, j = rm % HD;
        As[e] = Sraw[(size_t)b * NH * HD * HD + e] * inv[h * HD + i] * inv[C + h * HD + j] * tempf[h];
    }
    __syncthreads();
    if (tid < C) {
        const int h = tid / HD, i = tid % HD;
        float* rp = As + h * HD * HD + i * HD;
        float mx = -1e30f;
#pragma unroll
        for (int j = 0; j < HD; j++) mx = fmaxf(mx, rp[j]);
        float sum = 0.f;
#pragma unroll
        for (int j = 0; j < HD; j++) { rp[j] = __expf(rp[j] - mx); sum += rp[j]; }
        const float is = 1.f / sum;
#pragma unroll
        for (int j = 0; j < HD; j++) rp[j] *= is;
    }
    __syncthreads();
    const int idx = blockIdx.x * 256 + tid;
    const int o = idx / C, dg = idx % C;
    const int h = dg / HD, d = dg % HD;
    const float* wp = woutf + o * C + h * HD;
    const float* Ap = As + h * HD * HD + d;
    float acc = 0.f;
#pragma unroll
    for (int c2 = 0; c2 < HD; c2++) acc += wp[c2] * Ap[c2 * HD];
    Mb[(size_t)b * C * C + afrag_idx(o, dg)] = f2bfu(acc);
}

extern "C" void kernel_launch(void* const* d_in, const int* in_sizes, int n_in,
                              void* d_out, int out_size, void* d_ws, size_t ws_size,
                              hipStream_t stream) {
    const void* x    = d_in[0];
    const void* wqkv = d_in[1];
    const void* wdw  = d_in[2];
    const void* wout = d_in[3];
    const void* temp = d_in[4];

    char* w = (char*)d_ws;
    int* flag = (int*)w;                          w += 64;
    unsigned short* wqb = (unsigned short*)w;     w += (size_t)C3 * C * 2;
    unsigned short* Mb  = (unsigned short*)w;     w += (size_t)8 * C * C * 2;
    float* wdwf  = (float*)w;                     w += (size_t)C3 * 9 * 4;
    float* woutf = (float*)w;                     w += (size_t)C * C * 4;
    float* tempf = (float*)w;                     w += 64;
    float* normsum = (float*)w;                   w += (size_t)8 * 2 * C * 4;
    float* Sraw  = (float*)w;                     w += (size_t)8 * NH * HD * HD * 4;
    unsigned short* qkv0 = (unsigned short*)w;    w += (size_t)8 * C3 * HW * 2;
    unsigned short* qkv1 = (unsigned short*)w;

    probe_dtype<<<1, 256, 0, stream>>>((const unsigned int*)x, flag);
    prep<<<432, 256, 0, stream>>>(wqkv, wdw, wout, temp, flag, wqb, wdwf, woutf,
                                  tempf, Sraw, normsum);
    // qkv0[b] = Wqkv @ x_b  (bf16 out, 9 m-tiles)
    gemm_mfma<<<dim3(HW / 128, 8), 512, 0, stream>>>(
        x, wqb, qkv0, flag, (size_t)C * HW, 0, (size_t)C3 * HW, 0, 9, 0, 0);
    dwconv<<<dim3(8, C3, 8), 256, 0, stream>>>(qkv0, wdwf, qkv1, normsum);
    attn_gram<<<dim3(8, NH, 8), 256, 0, stream>>>(qkv1, Sraw);
    buildM<<<dim3(144, 8), 256, 0, stream>>>(Sraw, normsum, tempf, woutf, Mb);
    // out_b = M_b @ v_b  (dtype per flag, 3 m-tiles)
    gemm_mfma<<<dim3(HW / 128, 8), 512, 0, stream>>>(
        qkv1, Mb, d_out, flag, (size_t)C3 * HW, (size_t)2 * C * HW, (size_t)C * HW,
        C * C, 3, 1, 1);
}